// Round 8
// baseline (54.126 us; speedup 1.0000x reference)
//
#include <hip/hip_runtime.h>

// Shapes fixed by setup_inputs(): B=4, L=1024, A=5, KNN=32, K=16.
// Output: [B, L, KNN, A*A*K] f32 = 209.7 MB — write-bound (fill floor ~31us).
// R1: 64B/thread stores -> 4x write amplification (69us).
// R2: lane-contiguous f32x4 stores -> 48us. R4: +nt, 4 f4/thread -> 46us.
// R5: LDS two-phase regressed (52.8). R6: split kernels regressed (50.9);
//     near-load-free pure stream ALSO ~4.6 TB/s -> loads exonerated.
// R7: 32KB wave streams, 1600 blocks -> 47.6us. Stream shape at 6400 waves
//     didn't help.
// R8: fillBuffer-mimic: 512 blocks (2/CU, 2 waves/SIMD, like fillBuffer's
//     ~0.85 blocks/CU), each wave drains a CONTIGUOUS 100KB span in 100
//     back-to-back 1KB stores. Tests "few deep streams + per-wave pipeline
//     depth" as the 4.6-vs-6.9 TB/s mechanism.
constexpr int A_DIM   = 5;
constexpr int PAIRS   = 25;    // A*A
constexpr int KNN     = 32;
constexpr int L_DIM   = 1024;
constexpr int B_DIM   = 4;
constexpr int N_EDGES = B_DIM * L_DIM * KNN;        // 131,072
constexpr int TOTAL_F4 = N_EDGES * PAIRS * 4;       // 13,107,200 f32x4
constexpr int N_BLOCKS = 512;                       // 2 per CU
constexpr int N_WAVES  = N_BLOCKS * 4;              // 2048
constexpr int F4_PER_WAVE = TOTAL_F4 / N_WAVES;     // 6400 (100 KB contiguous)
constexpr int ITERS       = F4_PER_WAVE / 64;       // 100 stores per wave
// 1/sqrt(2*3.1415926)  (reference uses pi literal 3.1415926)
constexpr float INV_SQRT_2PI = 0.39894228f;

typedef float f32x4 __attribute__((ext_vector_type(4)));

__global__ __launch_bounds__(256) void gauss_rbf_kernel(
    const float* __restrict__ X,           // [B,L,A,3]
    const int*   __restrict__ E_idx,       // [B,L,KNN]
    const float* __restrict__ mask_atoms,  // [B,L,A]
    const float* __restrict__ mask_attend, // [B,L,KNN]
    const float* __restrict__ means,       // [16]
    const float* __restrict__ stds,        // [16]
    const float* __restrict__ mul,         // [25]
    const float* __restrict__ bias,        // [25]
    f32x4*       __restrict__ out4)        // 13,107,200 f32x4s
{
    const int tid  = threadIdx.x;
    const int lane = tid & 63;
    const int wave = tid >> 6;
    const int c    = lane & 3;             // channel quartet, loop-invariant

    // per-thread channel constants (4 broadcast lines, once per 100 iters)
    f32x4 mu4, iv4, co4;
#pragma unroll
    for (int t = 0; t < 4; ++t) {
        const int   k   = c * 4 + t;
        const float sd  = fabsf(stds[k]) + 0.01f;
        const float inv = __builtin_amdgcn_rcpf(sd);   // ~1 ulp; thr 3.3e-2
        mu4[t] = means[k];
        iv4[t] = inv;
        co4[t] = inv * INV_SQRT_2PI;
    }

    // each wave owns a contiguous span of 6400 f32x4 (100 KB)
    const unsigned w     = blockIdx.x * 4u + (unsigned)wave;
    const unsigned wbase = w * (unsigned)F4_PER_WAVE + (unsigned)lane;

#pragma unroll 4
    for (int it = 0; it < ITERS; ++it) {
        const unsigned fidx = wbase + (unsigned)it * 64u;  // f32x4 index
        const unsigned q    = fidx >> 2;          // (edge,pair); 16 consec/wave
        const unsigned e    = q / PAIRS;          // magic-mul
        const int      pair = (int)(q - e * PAIRS);
        const int      i    = pair / A_DIM;       // neighbor atom
        const int      j    = pair - i * A_DIM;   // center atom

        const unsigned bl = e >> 5;               // b*L + l  (KNN=32)
        const unsigned b  = bl >> 10;             // L=1024
        const int      n  = E_idx[e];
        const unsigned bn = (b << 10) | (unsigned)n;

        // L1/L2-resident gathers; a wave-iter touches 1-2 edges
        const float* xn = X + ((size_t)bn * A_DIM + i) * 3;
        const float* xc = X + ((size_t)bl * A_DIM + j) * 3;
        const float dx = xn[0] - xc[0];
        const float dy = xn[1] - xc[1];
        const float dz = xn[2] - xc[2];
        const float D  = sqrtf(dx * dx + dy * dy + dz * dz);

        // both masks gathered at the NEIGHBOR residue (per reference)
        const float mi = mask_atoms[(size_t)bn * A_DIM + i];
        const float mj = mask_atoms[(size_t)bn * A_DIM + j];

        const float x   = (mul[pair] * D + bias[pair]) * (mi * mj);
        const float att = mask_attend[e];

        const float z0 = (x - mu4.x) * iv4.x;
        const float z1 = (x - mu4.y) * iv4.y;
        const float z2 = (x - mu4.z) * iv4.z;
        const float z3 = (x - mu4.w) * iv4.w;
        f32x4 o;
        o.x = (co4.x * att) * __expf(-0.5f * z0 * z0);
        o.y = (co4.y * att) * __expf(-0.5f * z1 * z1);
        o.z = (co4.z * att) * __expf(-0.5f * z2 * z2);
        o.w = (co4.w * att) * __expf(-0.5f * z3 * z3);

        // back-to-back contiguous 1 KB wave-stores within a 100 KB span
        __builtin_nontemporal_store(o, &out4[fidx]);
    }
}

extern "C" void kernel_launch(void* const* d_in, const int* in_sizes, int n_in,
                              void* d_out, int out_size, void* d_ws, size_t ws_size,
                              hipStream_t stream) {
    const float* X           = (const float*)d_in[0];
    const int*   E_idx       = (const int*)  d_in[1];
    const float* mask_atoms  = (const float*)d_in[2];
    const float* mask_attend = (const float*)d_in[3];
    const float* means       = (const float*)d_in[4];
    const float* stds        = (const float*)d_in[5];
    const float* mul         = (const float*)d_in[6];
    const float* bias        = (const float*)d_in[7];
    f32x4*       out4        = (f32x4*)d_out;

    gauss_rbf_kernel<<<N_BLOCKS, 256, 0, stream>>>(
        X, E_idx, mask_atoms, mask_attend, means, stds, mul, bias, out4);
}

// Round 9
// 49.400 us; speedup vs baseline: 1.0957x; 1.0957x over previous
//
#include <hip/hip_runtime.h>

// Shapes fixed by setup_inputs(): B=4, L=1024, A=5, KNN=32, K=16.
// Output: [B, L, KNN, A*A*K] f32 = 209.7 MB — write-bound (fill floor ~31us).
// R1: 64B/thread stores -> 4x write amplification (69us).
// R2: lane-contiguous f32x4 -> 48us. R4: +nt, 4 f4/thread -> 46.2us (best).
// R5: LDS two-phase 52.8. R6: split kernels 50.9 (pure stream ALSO ~4.6TB/s).
// R7: private 32KB wave spans 47.6. R8: private 100KB wave spans 54.1.
//     Pattern: more PRIVATE per-wave contiguity = worse. fillBuffer (6.8TB/s)
//     is GRID-STRIDE: all resident waves share one contiguous ~1MB moving
//     frontier -> global DRAM row/channel locality.
// R9: grid-stride mimic: 1024 blocks (4/CU, all resident), 50 iters, stride
//     = grid (4MB collective frontier per iteration). Decode/compute = R4.
constexpr int A_DIM   = 5;
constexpr int PAIRS   = 25;    // A*A
constexpr int KNN     = 32;
constexpr int L_DIM   = 1024;
constexpr int B_DIM   = 4;
constexpr int N_EDGES = B_DIM * L_DIM * KNN;        // 131,072
constexpr int TOTAL_F4 = N_EDGES * PAIRS * 4;       // 13,107,200 f32x4
constexpr int N_BLOCKS = 1024;                      // 4 per CU, all resident
constexpr int STRIDE   = N_BLOCKS * 256;            // 262,144 f32x4 = 4 MB
constexpr int ITERS    = TOTAL_F4 / STRIDE;         // 50 (exact)
// 1/sqrt(2*3.1415926)  (reference uses pi literal 3.1415926)
constexpr float INV_SQRT_2PI = 0.39894228f;

typedef float f32x4 __attribute__((ext_vector_type(4)));

__global__ __launch_bounds__(256) void gauss_rbf_kernel(
    const float* __restrict__ X,           // [B,L,A,3]
    const int*   __restrict__ E_idx,       // [B,L,KNN]
    const float* __restrict__ mask_atoms,  // [B,L,A]
    const float* __restrict__ mask_attend, // [B,L,KNN]
    const float* __restrict__ means,       // [16]
    const float* __restrict__ stds,        // [16]
    const float* __restrict__ mul,         // [25]
    const float* __restrict__ bias,        // [25]
    f32x4*       __restrict__ out4)        // 13,107,200 f32x4s
{
    const int tid = threadIdx.x;
    const int c   = tid & 3;               // channel quartet, loop-invariant
                                           // (STRIDE % 4 == 0)

    // per-thread channel constants (4 broadcast lines, once per 50 iters)
    f32x4 mu4, iv4, co4;
#pragma unroll
    for (int t = 0; t < 4; ++t) {
        const int   k   = c * 4 + t;
        const float sd  = fabsf(stds[k]) + 0.01f;
        const float inv = __builtin_amdgcn_rcpf(sd);   // ~1 ulp; thr 3.3e-2
        mu4[t] = means[k];
        iv4[t] = inv;
        co4[t] = inv * INV_SQRT_2PI;
    }

    const unsigned base = blockIdx.x * 256u + (unsigned)tid;

#pragma unroll 5
    for (int it = 0; it < ITERS; ++it) {
        // grid-stride: whole chip writes one contiguous 4 MB chunk per iter
        const unsigned fidx = base + (unsigned)it * (unsigned)STRIDE;
        const unsigned q    = fidx >> 2;          // (edge,pair); 16 consec/wave
        const unsigned e    = q / PAIRS;          // magic-mul
        const int      pair = (int)(q - e * PAIRS);
        const int      i    = pair / A_DIM;       // neighbor atom
        const int      j    = pair - i * A_DIM;   // center atom

        const unsigned bl = e >> 5;               // b*L + l  (KNN=32)
        const unsigned b  = bl >> 10;             // L=1024
        const int      n  = E_idx[e];
        const unsigned bn = (b << 10) | (unsigned)n;

        // L1/L2-resident gathers; a wave-iter touches 1-2 edges
        const float* xn = X + ((size_t)bn * A_DIM + i) * 3;
        const float* xc = X + ((size_t)bl * A_DIM + j) * 3;
        const float dx = xn[0] - xc[0];
        const float dy = xn[1] - xc[1];
        const float dz = xn[2] - xc[2];
        const float D  = sqrtf(dx * dx + dy * dy + dz * dz);

        // both masks gathered at the NEIGHBOR residue (per reference)
        const float mi = mask_atoms[(size_t)bn * A_DIM + i];
        const float mj = mask_atoms[(size_t)bn * A_DIM + j];

        const float x   = (mul[pair] * D + bias[pair]) * (mi * mj);
        const float att = mask_attend[e];

        const float z0 = (x - mu4.x) * iv4.x;
        const float z1 = (x - mu4.y) * iv4.y;
        const float z2 = (x - mu4.z) * iv4.z;
        const float z3 = (x - mu4.w) * iv4.w;
        f32x4 o;
        o.x = (co4.x * att) * __expf(-0.5f * z0 * z0);
        o.y = (co4.y * att) * __expf(-0.5f * z1 * z1);
        o.z = (co4.z * att) * __expf(-0.5f * z2 * z2);
        o.w = (co4.w * att) * __expf(-0.5f * z3 * z3);

        // lane-contiguous 1 KB wave-store into the shared moving frontier
        __builtin_nontemporal_store(o, &out4[fidx]);
    }
}

extern "C" void kernel_launch(void* const* d_in, const int* in_sizes, int n_in,
                              void* d_out, int out_size, void* d_ws, size_t ws_size,
                              hipStream_t stream) {
    const float* X           = (const float*)d_in[0];
    const int*   E_idx       = (const int*)  d_in[1];
    const float* mask_atoms  = (const float*)d_in[2];
    const float* mask_attend = (const float*)d_in[3];
    const float* means       = (const float*)d_in[4];
    const float* stds        = (const float*)d_in[5];
    const float* mul         = (const float*)d_in[6];
    const float* bias        = (const float*)d_in[7];
    f32x4*       out4        = (f32x4*)d_out;

    gauss_rbf_kernel<<<N_BLOCKS, 256, 0, stream>>>(
        X, E_idx, mask_atoms, mask_attend, means, stds, mul, bias, out4);
}

// Round 10
// 41.681 us; speedup vs baseline: 1.2986x; 1.1852x over previous
//
#include <hip/hip_runtime.h>

// Shapes fixed by setup_inputs(): B=4, L=1024, A=5, KNN=32, K=16.
// Output: [B, L, KNN, A*A*K] f32 = 209.7 MB — write-bound (fill floor ~31us).
// R1: 64B/thread stores -> 69us. R2: lane-contiguous f32x4, NO nt -> 48.1us.
// R4: +nt +4 f4/thread -> 46.2us (best). R5: LDS two-phase 52.8.
// R6: split kernels 50.9 (pure stream also ~4.8 TB/s). R7: 32KB wave spans
//     47.6. R8: 100KB wave spans 54.1. R9: grid-stride frontier 49.4.
//     => store GEOMETRY exhaustively falsified; cap ~4.6-4.8 TB/s regardless.
// R10: isolate the ONE never-A/B'd variable: the nt flag. fillBufferAligned
//     (6.8 TB/s) uses PLAIN stores through the L2/LLC write-combine path;
//     nt's no-allocate bit may force poorly-combined direct-to-MC writes,
//     explaining a geometry-insensitive cap. R4 structure, plain stores.
constexpr int A_DIM   = 5;
constexpr int PAIRS   = 25;    // A*A
constexpr int KNN     = 32;
constexpr int L_DIM   = 1024;
constexpr int B_DIM   = 4;
constexpr int N_EDGES = B_DIM * L_DIM * KNN;        // 131,072
constexpr int TOTAL_F4 = N_EDGES * PAIRS * 4;       // 13,107,200 f32x4
// 1/sqrt(2*3.1415926)  (reference uses pi literal 3.1415926)
constexpr float INV_SQRT_2PI = 0.39894228f;

typedef float f32x4 __attribute__((ext_vector_type(4)));

__global__ __launch_bounds__(256) void gauss_rbf_kernel(
    const float* __restrict__ X,           // [B,L,A,3]
    const int*   __restrict__ E_idx,       // [B,L,KNN]
    const float* __restrict__ mask_atoms,  // [B,L,A]
    const float* __restrict__ mask_attend, // [B,L,KNN]
    const float* __restrict__ means,       // [16]
    const float* __restrict__ stds,        // [16]
    const float* __restrict__ mul,         // [25]
    const float* __restrict__ bias,        // [25]
    f32x4*       __restrict__ out4)        // 13,107,200 f32x4s
{
    const int tid = threadIdx.x;
    const int c   = tid & 3;               // channel quartet, loop-invariant

    // per-thread channel constants (4 broadcast lines, once per 4 iters)
    f32x4 mu4, iv4, co4;
#pragma unroll
    for (int t = 0; t < 4; ++t) {
        const int   k   = c * 4 + t;
        const float sd  = fabsf(stds[k]) + 0.01f;
        const float inv = __builtin_amdgcn_rcpf(sd);   // ~1 ulp; thr 3.3e-2
        mu4[t] = means[k];
        iv4[t] = inv;
        co4[t] = inv * INV_SQRT_2PI;
    }

    const unsigned fbase = blockIdx.x * 1024u + (unsigned)tid;

#pragma unroll
    for (int u = 0; u < 4; ++u) {
        const unsigned fidx = fbase + 256u * u;   // f32x4 index
        const unsigned q    = fidx >> 2;          // (edge,pair); 16 consec/wave
        const unsigned e    = q / PAIRS;          // magic-mul
        const int      pair = (int)(q - e * PAIRS);
        const int      i    = pair / A_DIM;       // neighbor atom
        const int      j    = pair - i * A_DIM;   // center atom

        const unsigned bl = e >> 5;               // b*L + l  (KNN=32)
        const unsigned b  = bl >> 10;             // L=1024
        const int      n  = E_idx[e];
        const unsigned bn = (b << 10) | (unsigned)n;

        // L1/L2-resident gathers; a wave-iter touches 1-2 edges
        const float* xn = X + ((size_t)bn * A_DIM + i) * 3;
        const float* xc = X + ((size_t)bl * A_DIM + j) * 3;
        const float dx = xn[0] - xc[0];
        const float dy = xn[1] - xc[1];
        const float dz = xn[2] - xc[2];
        const float D  = sqrtf(dx * dx + dy * dy + dz * dz);

        // both masks gathered at the NEIGHBOR residue (per reference)
        const float mi = mask_atoms[(size_t)bn * A_DIM + i];
        const float mj = mask_atoms[(size_t)bn * A_DIM + j];

        const float x   = (mul[pair] * D + bias[pair]) * (mi * mj);
        const float att = mask_attend[e];

        const float z0 = (x - mu4.x) * iv4.x;
        const float z1 = (x - mu4.y) * iv4.y;
        const float z2 = (x - mu4.z) * iv4.z;
        const float z3 = (x - mu4.w) * iv4.w;
        f32x4 o;
        o.x = (co4.x * att) * __expf(-0.5f * z0 * z0);
        o.y = (co4.y * att) * __expf(-0.5f * z1 * z1);
        o.z = (co4.z * att) * __expf(-0.5f * z2 * z2);
        o.w = (co4.w * att) * __expf(-0.5f * z3 * z3);

        // PLAIN store (no nt): lane-contiguous 1 KB/instr through the
        // L2/LLC write-combine path — same route fillBufferAligned uses.
        out4[fidx] = o;
    }
}

extern "C" void kernel_launch(void* const* d_in, const int* in_sizes, int n_in,
                              void* d_out, int out_size, void* d_ws, size_t ws_size,
                              hipStream_t stream) {
    const float* X           = (const float*)d_in[0];
    const int*   E_idx       = (const int*)  d_in[1];
    const float* mask_atoms  = (const float*)d_in[2];
    const float* mask_attend = (const float*)d_in[3];
    const float* means       = (const float*)d_in[4];
    const float* stds        = (const float*)d_in[5];
    const float* mul         = (const float*)d_in[6];
    const float* bias        = (const float*)d_in[7];
    f32x4*       out4        = (f32x4*)d_out;

    const int grid = TOTAL_F4 / 1024;   // 12,800 blocks (exact)

    gauss_rbf_kernel<<<grid, 256, 0, stream>>>(
        X, E_idx, mask_atoms, mask_attend, means, stds, mul, bias, out4);
}

// Round 11
// 40.986 us; speedup vs baseline: 1.3206x; 1.0170x over previous
//
#include <hip/hip_runtime.h>

// Shapes fixed by setup_inputs(): B=4, L=1024, A=5, KNN=32, K=16.
// Output: [B, L, KNN, A*A*K] f32 = 209.7 MB — write-bound (fill floor ~31us).
// R1: 64B/thread stores -> 69us. R2: lane-contiguous f32x4, plain -> 48.1us.
// R4: nt + 4 f4/thread -> 46.2. R5-R9: geometry sweep under nt: 46-54us,
//     flat => geometry tests were confounded by nt.
// R10: R4 minus nt -> 41.7us (5.0 TB/s). nt was costing ~4.5us: no-allocate
//     bypasses L2 write-combining.
// R11: plain-store ladder continues: 1 f4/thr=48.1, 4 f4/thr=41.7 -> try
//     8 f4/thr (same structure, grid 6400). Tests per-wave store-pipeline
//     depth through the L2 path as the remaining lever.
constexpr int A_DIM   = 5;
constexpr int PAIRS   = 25;    // A*A
constexpr int KNN     = 32;
constexpr int L_DIM   = 1024;
constexpr int B_DIM   = 4;
constexpr int N_EDGES = B_DIM * L_DIM * KNN;        // 131,072
constexpr int TOTAL_F4 = N_EDGES * PAIRS * 4;       // 13,107,200 f32x4
constexpr int F4_PER_THREAD = 8;
constexpr int F4_PER_BLOCK  = 256 * F4_PER_THREAD;  // 2048
// 1/sqrt(2*3.1415926)  (reference uses pi literal 3.1415926)
constexpr float INV_SQRT_2PI = 0.39894228f;

typedef float f32x4 __attribute__((ext_vector_type(4)));

__global__ __launch_bounds__(256) void gauss_rbf_kernel(
    const float* __restrict__ X,           // [B,L,A,3]
    const int*   __restrict__ E_idx,       // [B,L,KNN]
    const float* __restrict__ mask_atoms,  // [B,L,A]
    const float* __restrict__ mask_attend, // [B,L,KNN]
    const float* __restrict__ means,       // [16]
    const float* __restrict__ stds,        // [16]
    const float* __restrict__ mul,         // [25]
    const float* __restrict__ bias,        // [25]
    f32x4*       __restrict__ out4)        // 13,107,200 f32x4s
{
    const int tid = threadIdx.x;
    const int c   = tid & 3;               // channel quartet, loop-invariant

    // per-thread channel constants (4 broadcast lines, once per 8 iters)
    f32x4 mu4, iv4, co4;
#pragma unroll
    for (int t = 0; t < 4; ++t) {
        const int   k   = c * 4 + t;
        const float sd  = fabsf(stds[k]) + 0.01f;
        const float inv = __builtin_amdgcn_rcpf(sd);   // ~1 ulp; thr 3.3e-2
        mu4[t] = means[k];
        iv4[t] = inv;
        co4[t] = inv * INV_SQRT_2PI;
    }

    const unsigned fbase = blockIdx.x * (unsigned)F4_PER_BLOCK + (unsigned)tid;

#pragma unroll
    for (int u = 0; u < F4_PER_THREAD; ++u) {
        const unsigned fidx = fbase + 256u * u;   // f32x4 index
        const unsigned q    = fidx >> 2;          // (edge,pair); 16 consec/wave
        const unsigned e    = q / PAIRS;          // magic-mul
        const int      pair = (int)(q - e * PAIRS);
        const int      i    = pair / A_DIM;       // neighbor atom
        const int      j    = pair - i * A_DIM;   // center atom

        const unsigned bl = e >> 5;               // b*L + l  (KNN=32)
        const unsigned b  = bl >> 10;             // L=1024
        const int      n  = E_idx[e];
        const unsigned bn = (b << 10) | (unsigned)n;

        // L1/L2-resident gathers; a wave-iter touches 1-2 edges
        const float* xn = X + ((size_t)bn * A_DIM + i) * 3;
        const float* xc = X + ((size_t)bl * A_DIM + j) * 3;
        const float dx = xn[0] - xc[0];
        const float dy = xn[1] - xc[1];
        const float dz = xn[2] - xc[2];
        const float D  = sqrtf(dx * dx + dy * dy + dz * dz);

        // both masks gathered at the NEIGHBOR residue (per reference)
        const float mi = mask_atoms[(size_t)bn * A_DIM + i];
        const float mj = mask_atoms[(size_t)bn * A_DIM + j];

        const float x   = (mul[pair] * D + bias[pair]) * (mi * mj);
        const float att = mask_attend[e];

        const float z0 = (x - mu4.x) * iv4.x;
        const float z1 = (x - mu4.y) * iv4.y;
        const float z2 = (x - mu4.z) * iv4.z;
        const float z3 = (x - mu4.w) * iv4.w;
        f32x4 o;
        o.x = (co4.x * att) * __expf(-0.5f * z0 * z0);
        o.y = (co4.y * att) * __expf(-0.5f * z1 * z1);
        o.z = (co4.z * att) * __expf(-0.5f * z2 * z2);
        o.w = (co4.w * att) * __expf(-0.5f * z3 * z3);

        // plain lane-contiguous 1 KB wave-store through L2 write-combine
        out4[fidx] = o;
    }
}

extern "C" void kernel_launch(void* const* d_in, const int* in_sizes, int n_in,
                              void* d_out, int out_size, void* d_ws, size_t ws_size,
                              hipStream_t stream) {
    const float* X           = (const float*)d_in[0];
    const int*   E_idx       = (const int*)  d_in[1];
    const float* mask_atoms  = (const float*)d_in[2];
    const float* mask_attend = (const float*)d_in[3];
    const float* means       = (const float*)d_in[4];
    const float* stds        = (const float*)d_in[5];
    const float* mul         = (const float*)d_in[6];
    const float* bias        = (const float*)d_in[7];
    f32x4*       out4        = (f32x4*)d_out;

    const int grid = TOTAL_F4 / F4_PER_BLOCK;   // 6,400 blocks (exact)

    gauss_rbf_kernel<<<grid, 256, 0, stream>>>(
        X, E_idx, mask_atoms, mask_attend, means, stds, mul, bias, out4);
}